// Round 1
// baseline (131.257 us; speedup 1.0000x reference)
//
#include <hip/hip_runtime.h>
#include <hip/hip_bf16.h>

// N=8192 speakers, M=10 utterances, D=128 emb. Loss = -mean_n logsoftmax(logits)[n,n]
// logits = clip(cos(last_n, centroid_k), 1e-6)*w + b.
// Identity used: loss_n = ln2*(log2(sum_k 2^{z_nk}) - z_nn), z = max(cos,1e-6)*w*log2e
// (b cancels). cos computed as bf16 MFMA dot of pre-normalized unit vectors.

typedef __attribute__((ext_vector_type(8))) short short8;
typedef __attribute__((ext_vector_type(4))) float f32x4;

#define NSPK 8192
#define DEMB 128
#define MUTT 10

// workspace layout (floats):
//   W[0]            : scalar loss accumulator
//   W[64 .. +4*8192): S_part[chunk][n]  (sum of 2^z per row per column-chunk)
//   W[32832 .. +8192): zdiag[n]
// byte 262144: last_bf  [8192][128] bf16 (unit-normalized)  (2 MB)
// byte 2359296: cent_bf [8192][128] bf16 (unit-normalized)  (2 MB)
#define WS_SPART 64
#define WS_ZDIAG 32832
#define WS_LASTB 262144
#define WS_CENTB 2359296

__global__ void k1_prep(const float* __restrict__ x,
                        float* __restrict__ W,
                        __hip_bfloat16* __restrict__ lastb,
                        __hip_bfloat16* __restrict__ centb) {
    const int n = blockIdx.x;      // speaker
    const int d = threadIdx.x;     // 128 threads = emb dim
    const float* xr = x + (size_t)n * (MUTT * DEMB);
    float s = 0.f, v = 0.f;
#pragma unroll
    for (int m = 0; m < MUTT; ++m) { v = xr[m * DEMB + d]; s += v; }
    const float c = s * 0.1f;      // centroid_d
    const float lastv = v;         // m = 9
    float sc = c * c, sl = lastv * lastv;
#pragma unroll
    for (int off = 1; off < 64; off <<= 1) {
        sc += __shfl_xor(sc, off);
        sl += __shfl_xor(sl, off);
    }
    __shared__ float red[4];
    const int wv = d >> 6;
    if ((d & 63) == 0) { red[wv * 2] = sc; red[wv * 2 + 1] = sl; }
    __syncthreads();
    sc = red[0] + red[2];
    sl = red[1] + red[3];
    const float ic = rsqrtf(sc), il = rsqrtf(sl);
    lastb[n * DEMB + d] = __float2bfloat16(lastv * il);
    centb[n * DEMB + d] = __float2bfloat16(c * ic);
    if (n == 0 && d == 0) W[0] = 0.f;   // zero loss accumulator (ws is poisoned)
}

// block = 256 threads (4 waves). Block tile: 64 rows x 2048 cols (chunk).
// Wave wv owns rows R0 + wv*16 .. +16 for the whole column loop; A fragments
// (last) are loaded to registers ONCE. B (centroids) staged per 64-col tile in
// LDS, row stride padded 128->136 bf16 to break the 16-way bank conflict.
__global__ __launch_bounds__(256, 2) void k2_main(
        const __hip_bfloat16* __restrict__ lastb,
        const __hip_bfloat16* __restrict__ centb,
        const float* __restrict__ wp,
        float* __restrict__ W) {
    const int tid  = threadIdx.x;
    const int lane = tid & 63;
    const int wv   = tid >> 6;
    const int quad = lane >> 4;
    const int l16  = lane & 15;
    const int R0   = blockIdx.x * 64;
    const int C0   = blockIdx.y * 2048;
    const float wlog2e = wp[0] * 1.44269504088896340736f;
    const float zmin   = 1e-6f * wlog2e;

    __shared__ __hip_bfloat16 Bs[64 * 136];

    // A fragments: A[m=lane&15][k=quad*8+j], rows R0+wv*16+l16, 4 K-chunks of 32
    short8 a[4];
    {
        const short* ap = (const short*)(lastb + (size_t)(R0 + wv * 16 + l16) * DEMB + quad * 8);
#pragma unroll
        for (int kc = 0; kc < 4; ++kc) a[kc] = *(const short8*)(ap + kc * 32);
    }

    const int myrow0 = R0 + wv * 16 + quad * 4;   // rows myrow0..+3 (reg idx)
    float racc[4] = {0.f, 0.f, 0.f, 0.f};

    for (int it = 0; it < 32; ++it) {
        const int c0 = C0 + it * 64;
        __syncthreads();   // previous-iteration readers done before overwrite
        {
            // stage 64 rows x 128 bf16 (16 KB): 1024 x 16B chunks, 4 per thread
            const uint4* src = (const uint4*)(centb + (size_t)c0 * DEMB);
#pragma unroll
            for (int i = 0; i < 4; ++i) {
                const int idx = tid + i * 256;
                const int row = idx >> 4, ch = idx & 15;
                *((uint4*)&Bs[row * 136 + ch * 8]) = src[row * 16 + ch];
            }
        }
        __syncthreads();
#pragma unroll
        for (int nt = 0; nt < 4; ++nt) {
            f32x4 acc = {0.f, 0.f, 0.f, 0.f};
            const short* bp = (const short*)&Bs[(nt * 16 + l16) * 136 + quad * 8];
#pragma unroll
            for (int kc = 0; kc < 4; ++kc) {
                short8 b = *(const short8*)(bp + kc * 32);
                acc = __builtin_amdgcn_mfma_f32_16x16x32_bf16(a[kc], b, acc, 0, 0, 0);
            }
            // C layout: col = lane&15, row = quad*4 + reg
            const int col = c0 + nt * 16 + l16;
#pragma unroll
            for (int r = 0; r < 4; ++r) {
                const float z = fmaxf(acc[r] * wlog2e, zmin);
                racc[r] += exp2f(z);
                if (col == myrow0 + r) W[WS_ZDIAG + col] = z;   // diagonal logit (log2 domain)
            }
        }
    }
    // reduce row sums across the 16 lanes (low 4 bits) holding the same rows
#pragma unroll
    for (int off = 1; off < 16; off <<= 1) {
#pragma unroll
        for (int r = 0; r < 4; ++r) racc[r] += __shfl_xor(racc[r], off);
    }
    if (l16 == 0) {
#pragma unroll
        for (int r = 0; r < 4; ++r)
            W[WS_SPART + blockIdx.y * NSPK + myrow0 + r] = racc[r];
    }
}

__global__ void k3_loss(float* __restrict__ W) {
    const int n = blockIdx.x * 256 + threadIdx.x;
    const float P = W[WS_SPART + n] + W[WS_SPART + NSPK + n] +
                    W[WS_SPART + 2 * NSPK + n] + W[WS_SPART + 3 * NSPK + n];
    float v = __log2f(P) - W[WS_ZDIAG + n];
#pragma unroll
    for (int off = 1; off < 64; off <<= 1) v += __shfl_xor(v, off);
    __shared__ float red[4];
    if ((threadIdx.x & 63) == 0) red[threadIdx.x >> 6] = v;
    __syncthreads();
    if (threadIdx.x == 0) atomicAdd(&W[0], red[0] + red[1] + red[2] + red[3]);
}

__global__ void k4_fin(const float* __restrict__ W, float* __restrict__ out) {
    out[0] = W[0] * (0.69314718055994530942f / (float)NSPK);
}

extern "C" void kernel_launch(void* const* d_in, const int* in_sizes, int n_in,
                              void* d_out, int out_size, void* d_ws, size_t ws_size,
                              hipStream_t stream) {
    const float* x = (const float*)d_in[0];
    const float* w = (const float*)d_in[1];
    // b (d_in[2]) cancels analytically — unused.
    float* W = (float*)d_ws;
    __hip_bfloat16* lastb = (__hip_bfloat16*)((char*)d_ws + WS_LASTB);
    __hip_bfloat16* centb = (__hip_bfloat16*)((char*)d_ws + WS_CENTB);

    k1_prep<<<NSPK, DEMB, 0, stream>>>(x, W, lastb, centb);
    k2_main<<<dim3(128, 4), 256, 0, stream>>>(lastb, centb, w, W);
    k3_loss<<<NSPK / 256, 256, 0, stream>>>(W);
    k4_fin<<<1, 1, 0, stream>>>(W, (float*)d_out);
}

// Round 2
// 123.242 us; speedup vs baseline: 1.0650x; 1.0650x over previous
//
#include <hip/hip_runtime.h>
#include <hip/hip_bf16.h>

// AngleProtoLoss: loss = -mean_n logsoftmax(clip(cos(last_n,cent_k),1e-6)*w+b)[n,n]
// Identity: loss_n = ln2*(log2(sum_k 2^{z_nk}) - z_nn), z = clamp(cos*w*log2e); b cancels.
// k1: centroids+norms, writes unit cent (bf16) and w*log2e-prescaled unit last (bf16),
//     fp32 diagonal z_nn, zeros the row-sum accumulator.
// k2: bf16 MFMA 16x16x32; wave owns 64 rows (A in regs), B tile (64 cols x 128) staged
//     via global_load_lds w/ XOR chunk swizzle; epilogue exp2 accumulates row sums.
// k3: single block: loss = ln2/N * sum_n (log2(S_n) - z_nn).

typedef __attribute__((ext_vector_type(8))) short short8;
typedef __attribute__((ext_vector_type(4))) float f32x4;

#define NSPK 8192
#define DEMB 128
#define MUTT 10
#define LOG2E 1.44269504088896340736f
#define LN2   0.69314718055994530942f

// workspace: floats [0,8192) = zdiag, [8192,16384) = zsum; then bf16 matrices
#define WS_ZDIAG 0
#define WS_ZSUM  8192
#define WS_LASTB 65536      // byte offset, 2 MB
#define WS_CENTB 2162688    // byte offset, 2 MB

__global__ __launch_bounds__(256) void k1_prep(const float* __restrict__ x,
                                               const float* __restrict__ wp,
                                               float* __restrict__ W,
                                               __hip_bfloat16* __restrict__ lastb,
                                               __hip_bfloat16* __restrict__ centb) {
    const int wv = threadIdx.x >> 6;
    const int l  = threadIdx.x & 63;
    const int n  = blockIdx.x * 4 + wv;           // one wave per speaker
    if (blockIdx.x < 32) W[WS_ZSUM + blockIdx.x * 256 + threadIdx.x] = 0.f;

    const float* xr = x + (size_t)n * (MUTT * DEMB) + 2 * l;   // lane owns dims 2l,2l+1
    float sx = 0.f, sy = 0.f, vx = 0.f, vy = 0.f;
#pragma unroll
    for (int m = 0; m < MUTT; ++m) {
        float2 t = *(const float2*)(xr + m * DEMB);
        vx = t.x; vy = t.y; sx += t.x; sy += t.y;
    }
    const float cx = sx * 0.1f, cy = sy * 0.1f;   // centroid dims
    float sl = vx * vx + vy * vy;                 // |last|^2 partial
    float sc = cx * cx + cy * cy;                 // |cent|^2 partial
    float dp = vx * cx + vy * cy;                 // last.cent partial (diag)
#pragma unroll
    for (int off = 1; off < 64; off <<= 1) {
        sl += __shfl_xor(sl, off);
        sc += __shfl_xor(sc, off);
        dp += __shfl_xor(dp, off);
    }
    const float il = rsqrtf(sl), ic = rsqrtf(sc);
    const float scale = wp[0] * LOG2E;
    const float as = il * scale;                  // prescale last by w*log2e
    __hip_bfloat162 lv, cv;
    lv.x = __float2bfloat16(vx * as); lv.y = __float2bfloat16(vy * as);
    cv.x = __float2bfloat16(cx * ic); cv.y = __float2bfloat16(cy * ic);
    *(__hip_bfloat162*)(lastb + n * DEMB + 2 * l) = lv;
    *(__hip_bfloat162*)(centb + n * DEMB + 2 * l) = cv;
    if (l == 0) {
        const float lo = scale >= 0.f ? 1e-6f * scale : -INFINITY;
        const float hi = scale >= 0.f ? INFINITY : 1e-6f * scale;
        W[WS_ZDIAG + n] = fminf(fmaxf(dp * il * ic * scale, lo), hi);
    }
}

// grid (32,16): 256-row block x 512-col chunk. 4 waves; wave owns 64 rows (4 row-tiles).
__global__ __launch_bounds__(256, 2) void k2_main(
        const __hip_bfloat16* __restrict__ lastb,
        const __hip_bfloat16* __restrict__ centb,
        const float* __restrict__ wp,
        float* __restrict__ W) {
    const int tid  = threadIdx.x;
    const int lane = tid & 63;
    const int wv   = tid >> 6;
    const int quad = lane >> 4;
    const int l16  = lane & 15;
    const int R0   = blockIdx.x * 256;
    const int C0   = blockIdx.y * 512;
    const float scale = wp[0] * LOG2E;
    const float lo = scale >= 0.f ? 1e-6f * scale : -INFINITY;
    const float hi = scale >= 0.f ? INFINITY : 1e-6f * scale;

    __shared__ uint4 Bs4[1024];   // 16 KB: 64 rows x 16 chunks of 16B, chunk XOR-swizzled
    char* Bsc = (char*)Bs4;

    // A fragments (held whole kernel): rows R0 + wv*64 + rt*16 + l16, k = quad*8 + kc*32
    short8 a[4][4];
    {
        const short* ap = (const short*)lastb + (size_t)(R0 + wv * 64 + l16) * DEMB + quad * 8;
#pragma unroll
        for (int rt = 0; rt < 4; ++rt)
#pragma unroll
            for (int kc = 0; kc < 4; ++kc)
                a[rt][kc] = *(const short8*)(ap + rt * 16 * DEMB + kc * 32);
    }

    // swizzled B-fragment byte offsets within a 16-row ntile: row=l16, chunk=(quad+4kc)^l16
    int roff[4];
#pragma unroll
    for (int kc = 0; kc < 4; ++kc)
        roff[kc] = l16 * 256 + (((quad + 4 * kc) ^ l16) << 4);

    const int srow = wv * 16 + (lane >> 4);   // staging row (+i*4), wave stages rows [wv*16, wv*16+16)
    const int sp   = lane & 15;               // slot position within row
    float racc[4][4] = {{0.f}};

    for (int it = 0; it < 8; ++it) {
        const int c0 = C0 + it * 64;
        __syncthreads();                      // prev-iter readers done before DMA overwrite
#pragma unroll
        for (int i = 0; i < 4; ++i) {
            const int row = srow + i * 4;
            const int c   = sp ^ (row & 15);  // XOR swizzle: slot p holds global chunk p^row
            const char* src = (const char*)centb + ((size_t)(c0 + row) << 8) + (c << 4);
            char* dst = Bsc + (wv * 4096 + i * 1024 + lane * 16);
            __builtin_amdgcn_global_load_lds(
                (const __attribute__((address_space(1))) unsigned int*)src,
                (__attribute__((address_space(3))) unsigned int*)dst, 16, 0, 0);
        }
        __syncthreads();                      // vmcnt(0) drain + barrier
#pragma unroll
        for (int nt = 0; nt < 4; ++nt) {
            short8 b[4];
#pragma unroll
            for (int kc = 0; kc < 4; ++kc)
                b[kc] = *(const short8*)(Bsc + nt * 4096 + roff[kc]);
#pragma unroll
            for (int rt = 0; rt < 4; ++rt) {
                f32x4 acc = {0.f, 0.f, 0.f, 0.f};
#pragma unroll
                for (int kc = 0; kc < 4; ++kc)
                    acc = __builtin_amdgcn_mfma_f32_16x16x32_bf16(a[rt][kc], b[kc], acc, 0, 0, 0);
                // C layout: col = l16, row = quad*4 + r; acc is already z (A prescaled)
#pragma unroll
                for (int r = 0; r < 4; ++r) {
                    const float z = fminf(fmaxf(acc[r], lo), hi);
                    racc[rt][r] += exp2f(z);
                }
            }
        }
    }
    // reduce row sums over the 16 l16-lanes holding the same rows
#pragma unroll
    for (int off = 1; off < 16; off <<= 1)
#pragma unroll
        for (int rt = 0; rt < 4; ++rt)
#pragma unroll
            for (int r = 0; r < 4; ++r)
                racc[rt][r] += __shfl_xor(racc[rt][r], off);
    if (l16 == 0) {
#pragma unroll
        for (int rt = 0; rt < 4; ++rt)
#pragma unroll
            for (int r = 0; r < 4; ++r)
                atomicAdd(&W[WS_ZSUM + R0 + wv * 64 + rt * 16 + quad * 4 + r], racc[rt][r]);
    }
}

__global__ __launch_bounds__(256) void k3_loss(const float* __restrict__ W,
                                               float* __restrict__ out) {
    float v = 0.f;
    for (int n = threadIdx.x; n < NSPK; n += 256)
        v += __log2f(W[WS_ZSUM + n]) - W[WS_ZDIAG + n];
#pragma unroll
    for (int off = 1; off < 64; off <<= 1) v += __shfl_xor(v, off);
    __shared__ float red[4];
    if ((threadIdx.x & 63) == 0) red[threadIdx.x >> 6] = v;
    __syncthreads();
    if (threadIdx.x == 0)
        out[0] = (red[0] + red[1] + red[2] + red[3]) * (LN2 / (float)NSPK);
}

extern "C" void kernel_launch(void* const* d_in, const int* in_sizes, int n_in,
                              void* d_out, int out_size, void* d_ws, size_t ws_size,
                              hipStream_t stream) {
    const float* x = (const float*)d_in[0];
    const float* w = (const float*)d_in[1];
    // b (d_in[2]) cancels analytically — unused.
    float* W = (float*)d_ws;
    __hip_bfloat16* lastb = (__hip_bfloat16*)((char*)d_ws + WS_LASTB);
    __hip_bfloat16* centb = (__hip_bfloat16*)((char*)d_ws + WS_CENTB);

    k1_prep<<<NSPK / 4, 256, 0, stream>>>(x, w, W, lastb, centb);
    k2_main<<<dim3(32, 16), 256, 0, stream>>>(lastb, centb, w, W);
    k3_loss<<<1, 256, 0, stream>>>(W, (float*)d_out);
}

// Round 3
// 114.574 us; speedup vs baseline: 1.1456x; 1.0757x over previous
//
#include <hip/hip_runtime.h>
#include <hip/hip_bf16.h>

// AngleProtoLoss: loss = -mean_n logsoftmax(clip(cos(last_n,cent_k),1e-6)*w+b)[n,n]
// Identity: loss_n = ln2*(log2(sum_k 2^{z_nk}) - z_nn), z = clamp(cos*w*log2e); b cancels.
// k1: centroids+norms -> unit cent (bf16), w*log2e-prescaled unit last (bf16), fp32 z_nn.
// k2: bf16 MFMA 16x16x32, wave owns 64 rows (A in regs), B staged via global_load_lds
//     with XOR chunk swizzle into DOUBLE-BUFFERED LDS (one barrier/iter, DMA(i+1)
//     overlaps compute(i)); epilogue native exp2, clamp in exp domain (monotone).
// k3: single block: loss = ln2/N * sum_n (log2(S_n) - z_nn).

typedef __attribute__((ext_vector_type(8))) short short8;
typedef __attribute__((ext_vector_type(4))) float f32x4;

#define NSPK 8192
#define DEMB 128
#define MUTT 10
#define LOG2E 1.44269504088896340736f
#define LN2   0.69314718055994530942f

// workspace: floats [0,8192) = zdiag, [8192,16384) = zsum; then bf16 matrices
#define WS_ZDIAG 0
#define WS_ZSUM  8192
#define WS_LASTB 65536      // byte offset, 2 MB
#define WS_CENTB 2162688    // byte offset, 2 MB

__global__ __launch_bounds__(256) void k1_prep(const float* __restrict__ x,
                                               const float* __restrict__ wp,
                                               float* __restrict__ W,
                                               __hip_bfloat16* __restrict__ lastb,
                                               __hip_bfloat16* __restrict__ centb) {
    const int wv = threadIdx.x >> 6;
    const int l  = threadIdx.x & 63;
    const int n  = blockIdx.x * 4 + wv;           // one wave per speaker
    if (blockIdx.x < 32) W[WS_ZSUM + blockIdx.x * 256 + threadIdx.x] = 0.f;

    const float* xr = x + (size_t)n * (MUTT * DEMB) + 2 * l;   // lane owns dims 2l,2l+1
    float sx = 0.f, sy = 0.f, vx = 0.f, vy = 0.f;
#pragma unroll
    for (int m = 0; m < MUTT; ++m) {
        float2 t = *(const float2*)(xr + m * DEMB);
        vx = t.x; vy = t.y; sx += t.x; sy += t.y;
    }
    const float cx = sx * 0.1f, cy = sy * 0.1f;   // centroid dims
    float sl = vx * vx + vy * vy;                 // |last|^2 partial
    float sc = cx * cx + cy * cy;                 // |cent|^2 partial
    float dp = vx * cx + vy * cy;                 // last.cent partial (diag)
#pragma unroll
    for (int off = 1; off < 64; off <<= 1) {
        sl += __shfl_xor(sl, off);
        sc += __shfl_xor(sc, off);
        dp += __shfl_xor(dp, off);
    }
    const float il = rsqrtf(sl), ic = rsqrtf(sc);
    const float scale = wp[0] * LOG2E;
    const float as = il * scale;                  // prescale last by w*log2e
    __hip_bfloat162 lv, cv;
    lv.x = __float2bfloat16(vx * as); lv.y = __float2bfloat16(vy * as);
    cv.x = __float2bfloat16(cx * ic); cv.y = __float2bfloat16(cy * ic);
    *(__hip_bfloat162*)(lastb + n * DEMB + 2 * l) = lv;
    *(__hip_bfloat162*)(centb + n * DEMB + 2 * l) = cv;
    if (l == 0) {
        const float lo = scale >= 0.f ? 1e-6f * scale : -INFINITY;
        const float hi = scale >= 0.f ? INFINITY : 1e-6f * scale;
        W[WS_ZDIAG + n] = fminf(fmaxf(dp * il * ic * scale, lo), hi);
    }
}

// grid (32,16): 256-row block x 512-col chunk. 4 waves; wave owns 64 rows (4 row-tiles).
__global__ __launch_bounds__(256, 2) void k2_main(
        const __hip_bfloat16* __restrict__ lastb,
        const __hip_bfloat16* __restrict__ centb,
        const float* __restrict__ wp,
        float* __restrict__ W) {
    const int tid  = threadIdx.x;
    const int lane = tid & 63;
    const int wv   = tid >> 6;
    const int quad = lane >> 4;
    const int l16  = lane & 15;
    const int R0   = blockIdx.x * 256;
    const int C0   = blockIdx.y * 512;
    const float scale = wp[0] * LOG2E;
    // clamp moved to exp domain (2^z monotone): e in [elo, ehi]
    const float c0  = __builtin_amdgcn_exp2f(1e-6f * scale);
    const float elo = scale >= 0.f ? c0 : 0.f;
    const float ehi = scale >= 0.f ? INFINITY : c0;

    __shared__ uint4 Bs4[2048];   // 2 x 16 KB double buffer, XOR chunk-swizzled
    char* Bsc = (char*)Bs4;

    const int srow = wv * 16 + quad;          // staging row (+i*4)
    const int sp   = l16;                     // slot within row

    // prologue: DMA tile 0 into buf 0 (overlaps the A-frag loads below)
#pragma unroll
    for (int i = 0; i < 4; ++i) {
        const int row = srow + i * 4;
        const int c   = sp ^ (row & 15);
        const char* src = (const char*)centb + ((size_t)(C0 + row) << 8) + (c << 4);
        char* dst = Bsc + (wv * 4096 + i * 1024 + lane * 16);
        __builtin_amdgcn_global_load_lds(
            (const __attribute__((address_space(1))) unsigned int*)src,
            (__attribute__((address_space(3))) unsigned int*)dst, 16, 0, 0);
    }

    // A fragments (held whole kernel): rows R0 + wv*64 + rt*16 + l16, k = quad*8 + kc*32
    short8 a[4][4];
    {
        const short* ap = (const short*)lastb + (size_t)(R0 + wv * 64 + l16) * DEMB + quad * 8;
#pragma unroll
        for (int rt = 0; rt < 4; ++rt)
#pragma unroll
            for (int kc = 0; kc < 4; ++kc)
                a[rt][kc] = *(const short8*)(ap + rt * 16 * DEMB + kc * 32);
    }

    // swizzled B-fragment byte offsets within a 16-row ntile: row=l16, chunk=(quad+4kc)^l16
    int roff[4];
#pragma unroll
    for (int kc = 0; kc < 4; ++kc)
        roff[kc] = l16 * 256 + (((quad + 4 * kc) ^ l16) << 4);

    float racc[4][4] = {{0.f}};

    for (int it = 0; it < 8; ++it) {
        // drains vmcnt -> DMA(it) landed; also all waves done reading buf[(it+1)&1]
        __syncthreads();
        if (it < 7) {
            const int c0n = C0 + (it + 1) * 64;
            char* bufn = Bsc + ((it + 1) & 1) * 16384;
#pragma unroll
            for (int i = 0; i < 4; ++i) {
                const int row = srow + i * 4;
                const int c   = sp ^ (row & 15);
                const char* src = (const char*)centb + ((size_t)(c0n + row) << 8) + (c << 4);
                char* dst = bufn + (wv * 4096 + i * 1024 + lane * 16);
                __builtin_amdgcn_global_load_lds(
                    (const __attribute__((address_space(1))) unsigned int*)src,
                    (__attribute__((address_space(3))) unsigned int*)dst, 16, 0, 0);
            }
        }
        const char* buf = Bsc + (it & 1) * 16384;
#pragma unroll
        for (int nt = 0; nt < 4; ++nt) {
            short8 b[4];
#pragma unroll
            for (int kc = 0; kc < 4; ++kc)
                b[kc] = *(const short8*)(buf + nt * 4096 + roff[kc]);
#pragma unroll
            for (int rt = 0; rt < 4; ++rt) {
                f32x4 acc = {0.f, 0.f, 0.f, 0.f};
#pragma unroll
                for (int kc = 0; kc < 4; ++kc)
                    acc = __builtin_amdgcn_mfma_f32_16x16x32_bf16(a[rt][kc], b[kc], acc, 0, 0, 0);
                // C layout: col = l16, row = quad*4 + r; acc is already z (A prescaled)
#pragma unroll
                for (int r = 0; r < 4; ++r) {
                    const float e = __builtin_amdgcn_exp2f(acc[r]);
                    racc[rt][r] += fminf(fmaxf(e, elo), ehi);
                }
            }
        }
    }
    // reduce row sums over the 16 l16-lanes holding the same rows
#pragma unroll
    for (int off = 1; off < 16; off <<= 1)
#pragma unroll
        for (int rt = 0; rt < 4; ++rt)
#pragma unroll
            for (int r = 0; r < 4; ++r)
                racc[rt][r] += __shfl_xor(racc[rt][r], off);
    if (l16 == 0) {
#pragma unroll
        for (int rt = 0; rt < 4; ++rt)
#pragma unroll
            for (int r = 0; r < 4; ++r)
                atomicAdd(&W[WS_ZSUM + R0 + wv * 64 + rt * 16 + quad * 4 + r], racc[rt][r]);
    }
}

__global__ __launch_bounds__(256) void k3_loss(const float* __restrict__ W,
                                               float* __restrict__ out) {
    float v = 0.f;
    for (int n = threadIdx.x; n < NSPK; n += 256)
        v += __log2f(W[WS_ZSUM + n]) - W[WS_ZDIAG + n];
#pragma unroll
    for (int off = 1; off < 64; off <<= 1) v += __shfl_xor(v, off);
    __shared__ float red[4];
    if ((threadIdx.x & 63) == 0) red[threadIdx.x >> 6] = v;
    __syncthreads();
    if (threadIdx.x == 0)
        out[0] = (red[0] + red[1] + red[2] + red[3]) * (LN2 / (float)NSPK);
}

extern "C" void kernel_launch(void* const* d_in, const int* in_sizes, int n_in,
                              void* d_out, int out_size, void* d_ws, size_t ws_size,
                              hipStream_t stream) {
    const float* x = (const float*)d_in[0];
    const float* w = (const float*)d_in[1];
    // b (d_in[2]) cancels analytically — unused.
    float* W = (float*)d_ws;
    __hip_bfloat16* lastb = (__hip_bfloat16*)((char*)d_ws + WS_LASTB);
    __hip_bfloat16* centb = (__hip_bfloat16*)((char*)d_ws + WS_CENTB);

    k1_prep<<<NSPK / 4, 256, 0, stream>>>(x, w, W, lastb, centb);
    k2_main<<<dim3(32, 16), 256, 0, stream>>>(lastb, centb, w, W);
    k3_loss<<<1, 256, 0, stream>>>(W, (float*)d_out);
}